// Round 7
// baseline (342.680 us; speedup 1.0000x reference)
//
#include <hip/hip_runtime.h>
#include <hip/hip_bf16.h>

#define C_NUM 100000
#define D_EMB 512
#define N_BATCH 512
#define SCALE_F 30.0f
#define MARGIN_F 0.4f
#define H_F 0.333f
#define NTILES 1563          // ceil(100000/64)

typedef __attribute__((ext_vector_type(8))) short bf16x8;
typedef __attribute__((ext_vector_type(4))) short bf16x4;
typedef __attribute__((ext_vector_type(4))) float f32x4;
typedef __attribute__((ext_vector_type(16))) float f32x16;

static __device__ __forceinline__ short f2bf(float f) {
  __hip_bfloat16 h = __float2bfloat16(f);
  union { __hip_bfloat16 b; short s; } u;
  u.b = h;
  return u.s;
}

static __device__ __forceinline__ float sq4(f32x4 v) {
  return v[0]*v[0] + v[1]*v[1] + v[2]*v[2] + v[3]*v[3];
}

// ---------------------------------------------------------------------------
// Kernel 1: per-row L2 norm of embeddings; unit-normalized rows as bf16.
// ---------------------------------------------------------------------------
__global__ __launch_bounds__(64) void k_rownorm(const float* __restrict__ emb,
                                                short* __restrict__ Aunit,
                                                float* __restrict__ norms) {
  const int i = blockIdx.x;
  const int l = threadIdx.x;
  const f32x4* row = reinterpret_cast<const f32x4*>(emb + (size_t)i * D_EMB);
  f32x4 v0 = row[l];
  f32x4 v1 = row[l + 64];
  float ss = sq4(v0) + sq4(v1);
#pragma unroll
  for (int m = 1; m < 64; m <<= 1) ss += __shfl_xor(ss, m);
  float nrm = sqrtf(ss);
  float inv = 1.0f / nrm;
  bf16x4 o0, o1;
#pragma unroll
  for (int q = 0; q < 4; ++q) { o0[q] = f2bf(v0[q] * inv); o1[q] = f2bf(v1[q] * inv); }
  bf16x4* dst = reinterpret_cast<bf16x4*>(Aunit + (size_t)i * D_EMB);
  dst[l] = o0;
  dst[l + 64] = o1;
  if (l == 0) norms[i] = nrm;
}

// ---------------------------------------------------------------------------
// Kernel 2: batch mean / unbiased std -> adaptive margin per row.
// ---------------------------------------------------------------------------
__global__ __launch_bounds__(512) void k_stats(const float* __restrict__ norms,
                                               float* __restrict__ marg) {
  __shared__ float red[8];
  const int t = threadIdx.x;
  const int lane = t & 63, wid = t >> 6;
  float x = norms[t];
  float s = x;
#pragma unroll
  for (int m = 1; m < 64; m <<= 1) s += __shfl_xor(s, m);
  if (lane == 0) red[wid] = s;
  __syncthreads();
  float tot = 0.f;
#pragma unroll
  for (int q = 0; q < 8; ++q) tot += red[q];
  const float mean = tot / 512.f;
  __syncthreads();
  float d = x - mean;
  float s2 = d * d;
#pragma unroll
  for (int m = 1; m < 64; m <<= 1) s2 += __shfl_xor(s2, m);
  if (lane == 0) red[wid] = s2;
  __syncthreads();
  float tot2 = 0.f;
#pragma unroll
  for (int q = 0; q < 8; ++q) tot2 += red[q];
  const float stdv = sqrtf(tot2 / 511.f);   // ddof=1
  float msc = (x - mean) / (stdv + H_F);
  msc = fminf(1.f, fmaxf(-1.f, msc));
  marg[t] = MARGIN_F * (1.f + msc);
}

// ---------------------------------------------------------------------------
// Kernel 3: main — NO LDS, NO barriers. Each 256-thread block = 4 independent
// waves; wave w owns rows [rg*256 + w*64, +64) x classes [tile*64, +64).
// B-frags built directly from global f32 weight (cvt in regs); per-class
// sumsq accumulated in-register from the same loads, merged by one
// shfl_xor(32). Compiler is free to software-pipeline the barrier-less loop.
// ---------------------------------------------------------------------------
__global__ __launch_bounds__(256, 3) void k_main(const short* __restrict__ Aunit,
                                                 const float* __restrict__ weight,
                                                 const int* __restrict__ labels,
                                                 const float* __restrict__ marg,
                                                 float* __restrict__ partial,
                                                 float* __restrict__ tlogit) {
  const int tid  = threadIdx.x;
  const int bid  = blockIdx.x;
  const int tile = bid >> 1;           // 0..1562 (consecutive bids share tile -> L2 reuse)
  const int rg   = bid & 1;            // row group 0/1
  const int w    = tid >> 6;           // wave 0..3
  const int lane = tid & 63;
  const int l31  = lane & 31;
  const int lhi  = lane >> 5;          // 0..1
  const int rbase = rg * 256 + w * 64;
  const int c0 = tile * 64;

  const int gc0 = c0 + l31;
  const int gc1 = c0 + 32 + l31;
  const int gc0c = gc0 < C_NUM ? gc0 : C_NUM - 1;   // clamp addr (mask in epilogue)
  const int gc1c = gc1 < C_NUM ? gc1 : C_NUM - 1;

  const short* arow0 = Aunit + (size_t)(rbase + l31) * D_EMB;
  const short* arow1 = arow0 + (size_t)32 * D_EMB;
  const float* wrow0 = weight + (size_t)gc0c * D_EMB;
  const float* wrow1 = weight + (size_t)gc1c * D_EMB;

  f32x16 acc00, acc01, acc10, acc11;
#pragma unroll
  for (int q = 0; q < 16; ++q) { acc00[q] = 0.f; acc01[q] = 0.f; acc10[q] = 0.f; acc11[q] = 0.f; }
  float ssq0 = 0.f, ssq1 = 0.f;

  for (int k0 = 0; k0 < 512; k0 += 32) {
#pragma unroll
    for (int kk = 0; kk < 2; ++kk) {
      const int ka = k0 + kk * 16 + lhi * 8;   // 8 bf16 k-values per lane
      bf16x8 a0 = *reinterpret_cast<const bf16x8*>(arow0 + ka);
      bf16x8 a1 = *reinterpret_cast<const bf16x8*>(arow1 + ka);
      f32x4 w00 = *reinterpret_cast<const f32x4*>(wrow0 + ka);
      f32x4 w01 = *reinterpret_cast<const f32x4*>(wrow0 + ka + 4);
      f32x4 w10 = *reinterpret_cast<const f32x4*>(wrow1 + ka);
      f32x4 w11 = *reinterpret_cast<const f32x4*>(wrow1 + ka + 4);
      ssq0 += sq4(w00) + sq4(w01);
      ssq1 += sq4(w10) + sq4(w11);
      bf16x8 b0, b1;
#pragma unroll
      for (int e = 0; e < 4; ++e) {
        b0[e]     = f2bf(w00[e]);
        b0[e + 4] = f2bf(w01[e]);
        b1[e]     = f2bf(w10[e]);
        b1[e + 4] = f2bf(w11[e]);
      }
      acc00 = __builtin_amdgcn_mfma_f32_32x32x16_bf16(a0, b0, acc00, 0, 0, 0);
      acc01 = __builtin_amdgcn_mfma_f32_32x32x16_bf16(a0, b1, acc01, 0, 0, 0);
      acc10 = __builtin_amdgcn_mfma_f32_32x32x16_bf16(a1, b0, acc10, 0, 0, 0);
      acc11 = __builtin_amdgcn_mfma_f32_32x32x16_bf16(a1, b1, acc11, 0, 0, 0);
    }
  }

  // merge lhi-halves of per-class sumsq (each lane summed half the k-range)
  ssq0 += __shfl_xor(ssq0, 32);
  ssq1 += __shfl_xor(ssq1, 32);
  const float wv0 = ssq0 > 0.f ? rsqrtf(ssq0) : 0.f;
  const float wv1 = ssq1 > 0.f ? rsqrtf(ssq1) : 0.f;
  const bool v0ok = gc0 < C_NUM;
  const bool v1ok = gc1 < C_NUM;

  // ---- epilogue: margin at label, per-row exp-sums, partial write ----
  // C/D layout: col = lane&31, row = (reg&3) + 8*(reg>>2) + 4*(lane>>5)
#pragma unroll
  for (int mi = 0; mi < 2; ++mi) {
#pragma unroll
    for (int r = 0; r < 16; ++r) {
      const int rowf = (r & 3) + 8 * (r >> 2) + 4 * lhi;
      const int R = rbase + mi * 32 + rowf;
      const int lab = labels[R];
      float c0v = (mi ? acc10[r] : acc00[r]) * wv0;
      float c1v = (mi ? acc11[r] : acc01[r]) * wv1;
      float lg0 = SCALE_F * c0v;
      float lg1 = SCALE_F * c1v;
      if (lab == gc0) {
        float ct = fminf(1.f, fmaxf(-1.f, c0v));
        float lt = SCALE_F * cosf(acosf(ct) + marg[R]);
        lg0 = lt; tlogit[R] = lt;
      }
      if (lab == gc1) {
        float ct = fminf(1.f, fmaxf(-1.f, c1v));
        float lt = SCALE_F * cosf(acosf(ct) + marg[R]);
        lg1 = lt; tlogit[R] = lt;
      }
      float v = (v0ok ? __expf(lg0) : 0.f) + (v1ok ? __expf(lg1) : 0.f);
      v += __shfl_xor(v, 1);
      v += __shfl_xor(v, 2);
      v += __shfl_xor(v, 4);
      v += __shfl_xor(v, 8);
      v += __shfl_xor(v, 16);
      if (l31 == 0) partial[(size_t)tile * N_BATCH + R] = v;   // lanes 0 & 32: own rows
    }
  }
}

// ---------------------------------------------------------------------------
// Kernel 4: per-row reduce over tiles: term[r] = log(sum_t partial[t][r]) - tlogit[r]
// ---------------------------------------------------------------------------
__global__ __launch_bounds__(64) void k_reduce(const float* __restrict__ partial,
                                               const float* __restrict__ tlogit,
                                               float* __restrict__ term) {
  const int r = blockIdx.x;
  const int l = threadIdx.x;
  float s = 0.f;
  for (int b = l; b < NTILES; b += 64)
    s += partial[(size_t)b * N_BATCH + r];
#pragma unroll
  for (int m = 1; m < 64; m <<= 1) s += __shfl_xor(s, m);
  if (l == 0) term[r] = logf(s) - tlogit[r];
}

// ---------------------------------------------------------------------------
// Kernel 5: loss = mean(term)
// ---------------------------------------------------------------------------
__global__ __launch_bounds__(512) void k_final(const float* __restrict__ term,
                                               float* __restrict__ out) {
  __shared__ float red[8];
  const int t = threadIdx.x;
  const int lane = t & 63, wid = t >> 6;
  float v = term[t];
#pragma unroll
  for (int m = 1; m < 64; m <<= 1) v += __shfl_xor(v, m);
  if (lane == 0) red[wid] = v;
  __syncthreads();
  if (t == 0) {
    float tot = 0.f;
#pragma unroll
    for (int q = 0; q < 8; ++q) tot += red[q];
    out[0] = tot / 512.f;
  }
}

extern "C" void kernel_launch(void* const* d_in, const int* in_sizes, int n_in,
                              void* d_out, int out_size, void* d_ws, size_t ws_size,
                              hipStream_t stream) {
  const float* emb    = (const float*)d_in[0];
  const int*   labels = (const int*)d_in[1];
  const float* weight = (const float*)d_in[2];
  float* out = (float*)d_out;

  char* ws = (char*)d_ws;
  short* Aunit   = (short*)ws;                        // 512*512*2 = 524288 B
  float* norms   = (float*)(ws + 524288);             // 2 KiB
  float* marg    = (float*)(ws + 524288 + 2048);      // 2 KiB
  float* tlog    = (float*)(ws + 524288 + 4096);      // 2 KiB
  float* term    = (float*)(ws + 524288 + 6144);      // 2 KiB
  float* partial = (float*)(ws + 524288 + 8192);      // 1563*512*4 = 3201024 B

  k_rownorm<<<N_BATCH, 64, 0, stream>>>(emb, Aunit, norms);
  k_stats<<<1, 512, 0, stream>>>(norms, marg);
  k_main<<<NTILES * 2, 256, 0, stream>>>(Aunit, weight, labels, marg, partial, tlog);
  k_reduce<<<N_BATCH, 64, 0, stream>>>(partial, tlog, term);
  k_final<<<1, 512, 0, stream>>>(term, out);
}